// Round 10
// baseline (329.535 us; speedup 1.0000x reference)
//
#include <hip/hip_runtime.h>
#include <hip/hip_bf16.h>
#include <math.h>

#define B_   2
#define S_   2048
#define HID_ 2048
#define H_   16
#define HK_  4
#define D_   128
#define NH_  24          // H + 2*HK
#define QKVN 3072        // NH_ * D_
#define R_   64

typedef __attribute__((ext_vector_type(8))) _Float16 h8;     // 8 fp16 MFMA frag
typedef __attribute__((ext_vector_type(4))) _Float16 h4;     // 4 fp16 (b64)
typedef __attribute__((ext_vector_type(2))) _Float16 h2;
typedef __attribute__((ext_vector_type(4))) float f4;        // 16x16 accumulator
typedef __attribute__((ext_vector_type(16))) float f16v;     // 32x32 accumulator
typedef __attribute__((ext_vector_type(4))) unsigned u4;

// async global->LDS, 16B per lane; LDS dest = wave-uniform base + lane*16
#define GLOAD16(gp, lp) __builtin_amdgcn_global_load_lds(                      \
    (const __attribute__((address_space(1))) void*)(gp),                       \
    (__attribute__((address_space(3))) void*)(lp), 16, 0, 0)

__device__ __forceinline__ unsigned pk16(float a, float b) {
    auto v = __builtin_amdgcn_cvt_pkrtz(a, b);     // 2 x f32 -> packed 2 x f16
    return *reinterpret_cast<unsigned*>(&v);
}

// ---------------------------------------------------------------------------
// fused fp32 -> fp16 conversion of all three operands (one launch).
// ---------------------------------------------------------------------------
__global__ __launch_bounds__(256) void cvt3(
    const float* __restrict__ s0, _Float16* __restrict__ d0, int n0,
    const float* __restrict__ s1, _Float16* __restrict__ d1, int n1,
    const float* __restrict__ s2, _Float16* __restrict__ d2, int n2)
{
    int j = blockIdx.x * 256 + threadIdx.x;
    const float* s; _Float16* d;
    if (j < n0) { s = s0; d = d0; }
    else {
        j -= n0;
        if (j < n1) { s = s1; d = d1; }
        else { j -= n1; if (j >= n2) return; s = s2; d = d2; }
    }
    float4 a = ((const float4*)s)[j * 2];
    float4 b = ((const float4*)s)[j * 2 + 1];
    h8 h;
    h[0] = (_Float16)a.x; h[1] = (_Float16)a.y;
    h[2] = (_Float16)a.z; h[3] = (_Float16)a.w;
    h[4] = (_Float16)b.x; h[5] = (_Float16)b.y;
    h[6] = (_Float16)b.z; h[7] = (_Float16)b.w;
    ((h8*)d)[j] = h;
}

// ---------------------------------------------------------------------------
// QKV projection GEMM (round-9 config, frozen): 128x128 tile, BK=32 dbuf,
// 4 blocks/CU. FUSED epilogue: RMSNorm + RoPE + V-transpose.
// ---------------------------------------------------------------------------
__global__ __launch_bounds__(256, 4) void gemm_qkv(
    const _Float16* __restrict__ A, const _Float16* __restrict__ Bm,
    const float* __restrict__ cosT, const float* __restrict__ sinT,
    const float* __restrict__ qw, const float* __restrict__ kw,
    _Float16* __restrict__ Qh_g, _Float16* __restrict__ Kh_g,
    _Float16* __restrict__ Vt_g)
{
    __shared__ char smem_raw[34816];                         // 34 KB
    auto Ast  = (_Float16 (*)[128][32])(smem_raw);           // [2][128][32]
    auto Bst  = (_Float16 (*)[128][32])(smem_raw + 16384);   // [2][128][32]
    auto exch = (float (*)[128])(smem_raw + 32768);          // [2][128]

    const int tid = threadIdx.x;
    const int wave = tid >> 6, lane = tid & 63;
    const int l15 = lane & 15, l4 = lane >> 4;
    const int h  = blockIdx.x;            // head 0..23
    const int m0 = blockIdx.y * 128;      // token block
    const int n0 = h * 128;
    const int wm = (wave >> 1) * 64, wn = (wave & 1) * 64;
    const int K = HID_;

    f4 acc[16];
#pragma unroll
    for (int t = 0; t < 16; ++t) acc[t] = (f4){0.f, 0.f, 0.f, 0.f};

    const int srow = lane >> 2;                              // 0..15
    const int gsrc = (((lane & 3) ^ (srow & 3)) * 8);        // halfs
    const int rkey = l15 & 3;                                // read swizzle key

    auto STAGE = [&](int bf, int k0) {
#pragma unroll
        for (int t = 0; t < 2; ++t) {
            const int rbase = wave * 16 + 64 * t;            // wave-uniform
            const int grow  = rbase + srow;
            GLOAD16(A  + (size_t)(m0 + grow) * K + k0 + gsrc, &Ast[bf][rbase][0]);
            GLOAD16(Bm + (size_t)(n0 + grow) * K + k0 + gsrc, &Bst[bf][rbase][0]);
        }
    };

    STAGE(0, 0);
    int cur = 0;

    for (int k0 = 0; k0 < K; k0 += 32) {
        __syncthreads();   // vmcnt(0): tile-k0 landed; prev-buf reads done
        if (k0 + 32 < K) STAGE(cur ^ 1, k0 + 32);   // overlaps this compute

        h8 ahf[4], bhf[4];
#pragma unroll
        for (int i = 0; i < 4; ++i) {
            ahf[i] = *(const h8*)&Ast[cur][wm + i * 16 + l15][(l4 ^ rkey) * 8];
            bhf[i] = *(const h8*)&Bst[cur][wn + i * 16 + l15][(l4 ^ rkey) * 8];
        }
        __builtin_amdgcn_s_setprio(1);
#pragma unroll
        for (int i = 0; i < 4; ++i)
#pragma unroll
            for (int jj = 0; jj < 4; ++jj)
                acc[i * 4 + jj] = __builtin_amdgcn_mfma_f32_16x16x32_f16(
                    ahf[i], bhf[jj], acc[i * 4 + jj], 0, 0, 0);
        __builtin_amdgcn_s_setprio(0);
        cur ^= 1;
    }

    // ---------------- fused epilogue ----------------
    const int bb = m0 >> 11;              // batch
    const int s0 = m0 & 2047;             // seq base

    if (h < 20) {
        float sq[4][4];                   // [i][r]
#pragma unroll
        for (int i = 0; i < 4; ++i)
#pragma unroll
            for (int r = 0; r < 4; ++r) {
                float s = 0.f;
#pragma unroll
                for (int jj = 0; jj < 4; ++jj) {
                    float v = acc[i * 4 + jj][r];
                    s += v * v;
                }
                s += __shfl_xor(s, 1);
                s += __shfl_xor(s, 2);
                s += __shfl_xor(s, 4);
                s += __shfl_xor(s, 8);
                sq[i][r] = s;
            }
        const int half = wave & 1;
        if (l15 == 0) {
#pragma unroll
            for (int i = 0; i < 4; ++i)
#pragma unroll
                for (int r = 0; r < 4; ++r)
                    exch[half][wm + i * 16 + l4 * 4 + r] = sq[i][r];
        }
        __syncthreads();

        const float* wln = (h < 16) ? qw : kw;
        float wv[4];
#pragma unroll
        for (int jj = 0; jj < 4; ++jj) wv[jj] = wln[wn + jj * 16 + l15];

        const float QS = 0.08838834764831845f * 1.4426950408889634f;
        _Float16 (*Ld)[128] = (_Float16 (*)[128])smem_raw;   // 32 KB bounce

#pragma unroll
        for (int i = 0; i < 4; ++i) {
#pragma unroll
            for (int r = 0; r < 4; ++r) {
                const int row = wm + i * 16 + l4 * 4 + r;
                const int s  = s0 + row;
                float tot = sq[i][r] + exch[half ^ 1][row];
                float scale = rsqrtf(tot * (1.f / 128.f) + 1e-6f);
                float y[4];
#pragma unroll
                for (int jj = 0; jj < 4; ++jj)
                    y[jj] = acc[i * 4 + jj][r] * scale * wv[jj];

                float yr[4];
                if (wn == 0) {            // d < 64: RoPE rotates
                    const float* cp = cosT + ((size_t)bb * S_ + s) * R_;
                    const float* sp = sinT + ((size_t)bb * S_ + s) * R_;
                    float cs[4], sn[4];
#pragma unroll
                    for (int jj = 0; jj < 4; ++jj) {
                        cs[jj] = cp[jj * 16 + l15];
                        sn[jj] = sp[jj * 16 + l15];
                    }
                    yr[0] = y[0] * cs[0] - y[2] * sn[0];
                    yr[1] = y[1] * cs[1] - y[3] * sn[1];
                    yr[2] = y[2] * cs[2] + y[0] * sn[2];
                    yr[3] = y[3] * cs[3] + y[1] * sn[3];
                } else {
#pragma unroll
                    for (int jj = 0; jj < 4; ++jj) yr[jj] = y[jj];
                }

                const float os = (h < 16) ? QS : 1.f;
#pragma unroll
                for (int jj = 0; jj < 4; ++jj)
                    Ld[row][wn + jj * 16 + l15] = (_Float16)(yr[jj] * os);
            }
        }
        __syncthreads();

        _Float16* outb = (h < 16)
            ? Qh_g + (((size_t)bb * H_ + h) * S_ + s0) * D_
            : Kh_g + (((size_t)bb * HK_ + (h - 16)) * S_ + s0) * D_;
        const int rr = tid >> 4;
        const int d0 = (tid & 15) * 8;
#pragma unroll
        for (int it = 0; it < 8; ++it) {
            const int row = it * 16 + rr;
            *(h8*)(outb + (size_t)row * D_ + d0) = *(const h8*)&Ld[row][d0];
        }
    } else {
        const size_t vbase = ((size_t)bb * HK_ + (h - 20)) * D_ * S_;
#pragma unroll
        for (int i = 0; i < 4; ++i)
#pragma unroll
            for (int jj = 0; jj < 4; ++jj) {
                h4 pk;
#pragma unroll
                for (int r = 0; r < 4; ++r) pk[r] = (_Float16)acc[i * 4 + jj][r];
                const int d = wn + jj * 16 + l15;
                const int s = s0 + wm + i * 16 + l4 * 4;
                *(h4*)(Vt_g + vbase + (size_t)d * S_ + s) = pk;
            }
    }
}

// ---------------------------------------------------------------------------
// Dense projection GEMM (round-9 config, frozen): 128x128, BK=32 dbuf.
// ---------------------------------------------------------------------------
__global__ __launch_bounds__(256, 4) void gemm_dense(
    const _Float16* __restrict__ A, const _Float16* __restrict__ Bm,
    float* __restrict__ Cv, int M, int N, int K)
{
    __shared__ _Float16 Ast[2][128][32];
    __shared__ _Float16 Bst[2][128][32];

    const int tid = threadIdx.x;
    const int wave = tid >> 6, lane = tid & 63;
    const int l15 = lane & 15, l4 = lane >> 4;
    const int m0 = blockIdx.y * 128, n0 = blockIdx.x * 128;
    const int wm = (wave >> 1) * 64, wn = (wave & 1) * 64;

    f4 acc[16];
#pragma unroll
    for (int t = 0; t < 16; ++t) acc[t] = (f4){0.f, 0.f, 0.f, 0.f};

    const int srow = lane >> 2;
    const int gsrc = (((lane & 3) ^ (srow & 3)) * 8);
    const int rkey = l15 & 3;

    auto STAGE = [&](int bf, int k0) {
#pragma unroll
        for (int t = 0; t < 2; ++t) {
            const int rbase = wave * 16 + 64 * t;
            const int grow  = rbase + srow;
            GLOAD16(A  + (size_t)(m0 + grow) * K + k0 + gsrc, &Ast[bf][rbase][0]);
            GLOAD16(Bm + (size_t)(n0 + grow) * K + k0 + gsrc, &Bst[bf][rbase][0]);
        }
    };

    STAGE(0, 0);
    int cur = 0;

    for (int k0 = 0; k0 < K; k0 += 32) {
        __syncthreads();
        if (k0 + 32 < K) STAGE(cur ^ 1, k0 + 32);

        h8 ahf[4], bhf[4];
#pragma unroll
        for (int i = 0; i < 4; ++i) {
            ahf[i] = *(const h8*)&Ast[cur][wm + i * 16 + l15][(l4 ^ rkey) * 8];
            bhf[i] = *(const h8*)&Bst[cur][wn + i * 16 + l15][(l4 ^ rkey) * 8];
        }
        __builtin_amdgcn_s_setprio(1);
#pragma unroll
        for (int i = 0; i < 4; ++i)
#pragma unroll
            for (int jj = 0; jj < 4; ++jj)
                acc[i * 4 + jj] = __builtin_amdgcn_mfma_f32_16x16x32_f16(
                    ahf[i], bhf[jj], acc[i * 4 + jj], 0, 0, 0);
        __builtin_amdgcn_s_setprio(0);
        cur ^= 1;
    }

#pragma unroll
    for (int i = 0; i < 4; ++i)
#pragma unroll
        for (int jj = 0; jj < 4; ++jj)
#pragma unroll
            for (int r = 0; r < 4; ++r) {
                int row = m0 + wm + i * 16 + l4 * 4 + r;
                int col = n0 + wn + jj * 16 + l15;
                Cv[(size_t)row * N + col] = acc[i * 4 + jj][r];
            }
}

// ---------------------------------------------------------------------------
// MFMA flash attention, 32x32x16 MFMA with IN-REGISTER P (no P LDS round-trip).
// Swapped QK^T (mfma(K,Q)): acc S^T, lane holds col q=lane&31, rows kv =
// (reg&3)+8*(reg>>2)+4*(lane>>5). exp2 in place (fixed -8 bias in C-in).
// PV A-fragment (needs kv=(lane>>5)*8+j for row q=lane&31) is rebuilt from
// the acc registers with v_cvt_pkrtz pairs + v_permlane32_swap half-wave
// exchange (T12 mechanism) -- P never touches LDS. LDS traffic/block/tile:
// 160 KB (was 192); P-store bank conflicts eliminated. LDS 64 KB, 2 blk/CU.
// K/V staging + granule swizzle + 1-barrier dbuf loop carried over verbatim.
// ---------------------------------------------------------------------------
__global__ __launch_bounds__(256, 2) void flash_mfma(
    const _Float16* __restrict__ Qh_g, const _Float16* __restrict__ Kh_g,
    const _Float16* __restrict__ Vt_g, _Float16* __restrict__ Ao)
{
    __shared__ _Float16 Ksh[2][64][128];   // [buf][kv][d], granule-swizzled
    __shared__ _Float16 Vsh[2][128][64];   // [buf][d][kv], granule-swizzled

    const int tid = threadIdx.x;
    const int wave = tid >> 6, lane = tid & 63;
    const int l31 = lane & 31, hw = lane >> 5;   // half-wave id
    const int qb = blockIdx.x, head = blockIdx.y, b = blockIdx.z;
    const int kh = head >> 2;
    const int key = lane & 7;             // read-side swizzle key (row&7)

    // ---- Q B-fragments: lane holds Q[q0 + l31][j*16 + hw*8 .. +8] ----
    h8 qf[8];
    {
        const _Float16* qrow = Qh_g +
            (((size_t)b * H_ + head) * S_ + qb * 128 + wave * 32 + l31) * D_;
#pragma unroll
        for (int j = 0; j < 8; ++j)
            qf[j] = *(const h8*)(qrow + j * 16 + hw * 8);
    }

    f16v o[4];
#pragma unroll
    for (int t = 0; t < 4; ++t) o[t] = 0.f;
    float lp = 0.f;

    const size_t kvoff = ((size_t)b * HK_ + kh) * S_ * D_;
    const _Float16* kg = Kh_g + kvoff;   // (S, D)
    const _Float16* vg = Vt_g + kvoff;   // (D, S)

    // staging geometry (per wave: K rows wave*16..+15, V rows wave*32..+31)
    int krow[4], ksrc[4], vrow[4], vsrc[4];
#pragma unroll
    for (int t = 0; t < 4; ++t) {
        krow[t] = wave * 16 + t * 4 + (lane >> 4);            // kv row 0..63
        ksrc[t] = ((lane & 15) ^ (krow[t] & 7)) * 8;          // inv-swz col
        vrow[t] = wave * 32 + t * 8 + (lane >> 3);            // d row 0..127
        vsrc[t] = ((lane & 7) ^ (vrow[t] & 7)) * 8;           // inv-swz col
    }

    auto STAGE = [&](int bf, int kb) {
#pragma unroll
        for (int t = 0; t < 4; ++t)
            GLOAD16(kg + (size_t)(kb * 64 + krow[t]) * D_ + ksrc[t],
                    &Ksh[bf][wave * 16 + t * 4][0]);
#pragma unroll
        for (int t = 0; t < 4; ++t)
            GLOAD16(vg + (size_t)vrow[t] * S_ + kb * 64 + vsrc[t],
                    &Vsh[bf][wave * 32 + t * 8][0]);
    };

    STAGE(0, 0);
    int cur = 0;

    for (int kb = 0; kb < S_ / 64; ++kb) {
        __syncthreads();   // vmcnt(0): tile-kb stage landed; prev reads done
        if (kb + 1 < S_ / 64) STAGE(cur ^ 1, kb + 1);   // overlaps this compute

        // ---- QK^T swapped, 32x32x16: acc0 = kv 0..31, acc1 = kv 32..63 ----
        f16v a0 = -8.f, a1 = -8.f;        // exp2 bias in C-in
        __builtin_amdgcn_s_setprio(1);
#pragma unroll
        for (int j = 0; j < 8; ++j) {
            const int gc = ((2 * j + hw) ^ key) * 8;
            h8 kf0 = *(const h8*)&Ksh[cur][l31][gc];
            h8 kf1 = *(const h8*)&Ksh[cur][32 + l31][gc];
            a0 = __builtin_amdgcn_mfma_f32_32x32x16_f16(kf0, qf[j], a0, 0, 0, 0);
            a1 = __builtin_amdgcn_mfma_f32_32x32x16_f16(kf1, qf[j], a1, 0, 0, 0);
        }
        __builtin_amdgcn_s_setprio(0);

        // ---- exp2 in place + denominator partial ----
#pragma unroll
        for (int r = 0; r < 16; ++r) {
            a0[r] = exp2f(a0[r]);  lp += a0[r];
            a1[r] = exp2f(a1[r]);  lp += a1[r];
        }

        // ---- PV: per k-step s, rebuild P A-frag in registers ----
        __builtin_amdgcn_s_setprio(1);
#pragma unroll
        for (int s = 0; s < 4; ++s) {
            const f16v& pa = (s < 2) ? a0 : a1;
            const int base = (s & 1) * 8;
            unsigned d0 = pk16(pa[base + 0], pa[base + 1]);
            unsigned d1 = pk16(pa[base + 2], pa[base + 3]);
            unsigned d2 = pk16(pa[base + 4], pa[base + 5]);
            unsigned d3 = pk16(pa[base + 6], pa[base + 7]);
            // swap own high-half dwords with partner low-half dwords:
            // after: d0,d1 = frag dwords 0,1 ; d2,d3 = frag dwords 2,3
            asm volatile("v_permlane32_swap_b32 %0, %1" : "+v"(d0), "+v"(d2));
            asm volatile("v_permlane32_swap_b32 %0, %1" : "+v"(d1), "+v"(d3));
            u4 fw; fw.x = d0; fw.y = d1; fw.z = d2; fw.w = d3;
            h8 pfrag = __builtin_bit_cast(h8, fw);

            const int gv = ((2 * s + hw) ^ key) * 8;
#pragma unroll
            for (int t = 0; t < 4; ++t) {
                h8 vf = *(const h8*)&Vsh[cur][t * 32 + l31][gv];
                o[t] = __builtin_amdgcn_mfma_f32_32x32x16_f16(pfrag, vf, o[t], 0, 0, 0);
            }
        }
        __builtin_amdgcn_s_setprio(0);
        cur ^= 1;
    }

    // ---- softmax denominator + output ----
    float Linv = 1.f / (lp + __shfl_xor(lp, 32));   // full sum for q = l31

    const size_t obase = (((size_t)b * S_ + qb * 128 + wave * 32) * (H_ * D_))
                         + (size_t)head * D_;
#pragma unroll
    for (int r = 0; r < 16; ++r) {
        const int qr = (r & 3) + 8 * (r >> 2) + 4 * hw;   // q row of reg r
        float invr = __shfl(Linv, qr);
#pragma unroll
        for (int t = 0; t < 4; ++t) {
            Ao[obase + (size_t)qr * (H_ * D_) + t * 32 + l31] =
                (_Float16)(o[t][r] * invr);
        }
    }
}

// ---------------------------------------------------------------------------
extern "C" void kernel_launch(void* const* d_in, const int* in_sizes, int n_in,
                              void* d_out, int out_size, void* d_ws, size_t ws_size,
                              hipStream_t stream)
{
    const float* hidden  = (const float*)d_in[0];
    const float* cosT    = (const float*)d_in[1];
    const float* sinT    = (const float*)d_in[2];
    const float* w_qkv   = (const float*)d_in[3];
    const float* q_ln    = (const float*)d_in[4];
    const float* k_ln    = (const float*)d_in[5];
    const float* w_dense = (const float*)d_in[6];
    float* out = (float*)d_out;

    // workspace layout (bytes), NO aliasing:
    //   attn16   : 16,777,216  @ 0
    //   hidden16 : 16,777,216  @ 16,777,216
    //   wqkv16   : 12,582,912  @ 33,554,432
    //   Qh       : 16,777,216  @ 46,137,344
    //   Kh       :  4,194,304  @ 62,914,560
    //   Vt       :  4,194,304  @ 67,108,864
    //   wdense16 :  8,388,608  @ 71,303,168
    // total 79,691,776
    char* w = (char*)d_ws;
    _Float16* attn16   = (_Float16*)w;
    _Float16* hidden16 = (_Float16*)(w + 16777216);
    _Float16* wqkv16   = (_Float16*)(w + 33554432);
    _Float16* Qh       = (_Float16*)(w + 46137344);
    _Float16* Kh       = (_Float16*)(w + 62914560);
    _Float16* Vt       = (_Float16*)(w + 67108864);
    _Float16* wdense16 = (_Float16*)(w + 71303168);

    // 0) fp32 -> fp16 operand conversions (single fused launch)
    cvt3<<<9216, 256, 0, stream>>>(hidden,  hidden16, 1048576,
                                   w_qkv,   wqkv16,   786432,
                                   w_dense, wdense16, 524288);

    // 1) QKV projection with fused RMSNorm+RoPE+V-transpose epilogue
    gemm_qkv<<<dim3(NH_, (B_ * S_) / 128), 256, 0, stream>>>(
        hidden16, wqkv16, cosT, sinT, q_ln, k_ln, Qh, Kh, Vt);

    // 2) MFMA flash attention (32x32, in-register P) -> attn16 fp16
    flash_mfma<<<dim3(S_ / 128, H_, B_), 256, 0, stream>>>(Qh, Kh, Vt, attn16);

    // 3) dense projection (fp16 MFMA GEMM, fp32 out)
    gemm_dense<<<dim3(HID_ / 128, (B_ * S_) / 128), 256, 0, stream>>>(
        attn16, wdense16, out, B_ * S_, HID_, H_ * D_);
}